// Round 1
// baseline (2022.249 us; speedup 1.0000x reference)
//
#include <hip/hip_runtime.h>
#include <hip/hip_bf16.h>

constexpr int kB = 128;
constexpr int kT = 1024;
constexpr int kI = 64;
constexpr int kH = 512;
constexpr int kO = 32;
constexpr float kTau = 0.2f;
constexpr float kNoise = 0.05f;

__device__ __forceinline__ float fast_tanh(float x) {
    // tanh(x) = 1 - 2/(e^{2x}+1); exact limits at +-inf, ~1e-7 abs error.
    float e = __expf(2.0f * x);
    return 1.0f - 2.0f * __builtin_amdgcn_rcpf(e + 1.0f);
}

// One block per batch row b. 512 threads = one per hidden unit h.
// State x[h] in a register across all T steps. Per step:
//   - 6 low-rank dot products over H via LDS column reduce (waves 0..5)
//   - wave 7 stages u[b,t,0:64] into LDS (wave-uniform input row)
//   - input projection: 64 FMAs/thread with Win_w row held in VGPRs
__global__ __launch_bounds__(512) void scan_kernel(
    const float* __restrict__ u, const float* __restrict__ x0,
    const float* __restrict__ noise, const float* __restrict__ Win_w,
    const float* __restrict__ Win_b, const float* __restrict__ M_rnn,
    const float* __restrict__ N_rnn, const float* __restrict__ L_tb,
    const float* __restrict__ M_tb, const float* __restrict__ N_tb,
    float* __restrict__ traj, float* __restrict__ xfin)
{
    const int b = blockIdx.x;
    const int h = threadIdx.x;

    __shared__ float red[6 * kH];   // column-major: red[j*512 + h]
    __shared__ float res[8];        // 6 reduced scalars
    __shared__ float u_lds[kI];     // current step's input row

    // Per-thread weights in registers.
    float W[kI];
    #pragma unroll
    for (int i = 0; i < kI; i += 4) {
        float4 w = *(const float4*)&Win_w[h * kI + i];
        W[i] = w.x; W[i + 1] = w.y; W[i + 2] = w.z; W[i + 3] = w.w;
    }
    const float wb  = Win_b[h];
    const float Nr0 = N_rnn[h * 2], Nr1 = N_rnn[h * 2 + 1];
    const float Mt0 = M_tb[h * 2],  Mt1 = M_tb[h * 2 + 1];
    const float Nt0 = N_tb[h * 2],  Nt1 = N_tb[h * 2 + 1];
    const float sc_rnn = 1.0f / (float)kH;
    const float sc_tb  = 1.0f / ((float)kH * (float)kH);
    const float Mr0 = M_rnn[h * 2] * sc_rnn, Mr1 = M_rnn[h * 2 + 1] * sc_rnn;
    const float Lt0 = L_tb[h * 2] * sc_tb,   Lt1 = L_tb[h * 2 + 1] * sc_tb;

    float x = x0[b * kH + h];

    const float* up  = u + (size_t)b * kT * kI;
    const float* nzp = noise + (size_t)b * kH + h;     // noise[t][b][h]
    float* tp = traj + (size_t)b * kT * kH + h;        // traj[b][t][h]

    const int wid  = h >> 6;
    const int lane = h & 63;

    for (int t = 0; t < kT; ++t) {
        float r = fast_tanh(x);
        red[0 * kH + h] = r * Nr0;
        red[1 * kH + h] = r * Nr1;
        red[2 * kH + h] = r * Mt0;
        red[3 * kH + h] = r * Mt1;
        red[4 * kH + h] = r * Nt0;
        red[5 * kH + h] = r * Nt1;
        float nz = nzp[(size_t)t * kB * kH];           // prefetch noise
        __syncthreads();
        if (wid < 6) {
            const float* c = red + wid * kH + lane;
            float s = c[0] + c[64] + c[128] + c[192] +
                      c[256] + c[320] + c[384] + c[448];
            #pragma unroll
            for (int off = 32; off; off >>= 1) s += __shfl_xor(s, off);
            if (lane == 0) res[wid] = s;
        } else if (wid == 7) {
            u_lds[lane] = up[t * kI + lane];           // wave-uniform row
        }
        __syncthreads();
        const float a0 = res[0], a1 = res[1];
        const float m0 = res[2], m1 = res[3];
        const float n0 = res[4], n1 = res[5];

        float ip = wb;
        #pragma unroll
        for (int i = 0; i < kI; i += 4) {
            float4 uv = *(const float4*)&u_lds[i];
            ip += uv.x * W[i] + uv.y * W[i + 1] + uv.z * W[i + 2] + uv.w * W[i + 3];
        }

        const float rec = a0 * Mr0 + a1 * Mr1 + (m0 * n0) * Lt0 + (m1 * n1) * Lt1 + ip;
        x = (1.0f - kTau) * x + kNoise * nz + kTau * rec;
        tp[(size_t)t * kH] = x;
    }
    xfin[b * kH + h] = x;
}

// out[row][o] = sum_h tanh(traj[row][h]) * Wout_w[o][h] + Wout_b[o]
// rows = B*T = 131072. Block = 256 threads handles 32 rows.
// Wout (32x512) staged once per block in LDS (stride 516 to spread banks);
// A staged in 32x64 chunks with tanh applied at load.
__global__ __launch_bounds__(256) void out_kernel(
    const float* __restrict__ traj, const float* __restrict__ Wout_w,
    const float* __restrict__ Wout_b, float* __restrict__ out)
{
    __shared__ float Ws[kO][kH + 4];   // 32 x 516 fp32 = 66 KB
    __shared__ float As[32][64];       // 8 KB chunk

    const int tid  = threadIdx.x;
    const int row0 = blockIdx.x * 32;

    // Stage Wout: 16384 floats, 64 per thread.
    {
        const int o  = tid >> 3;
        const int cb = (tid & 7) * 64;
        #pragma unroll
        for (int j = 0; j < 64; j += 4) {
            float4 w = *(const float4*)&Wout_w[o * kH + cb + j];
            *(float4*)&Ws[o][cb + j] = w;
        }
    }

    const int o  = tid & 31;
    const int rg = tid >> 5;           // row group: 4 rows each
    float acc0 = 0.f, acc1 = 0.f, acc2 = 0.f, acc3 = 0.f;

    for (int kb = 0; kb < kH; kb += 64) {
        __syncthreads();               // protects Ws (first iter) / As reuse
        {
            const int flat = tid * 8;
            const int r = flat >> 6;
            const int c = flat & 63;
            const float* src = traj + (size_t)(row0 + r) * kH + kb + c;
            #pragma unroll
            for (int j = 0; j < 8; j += 4) {
                float4 v = *(const float4*)&src[j];
                v.x = fast_tanh(v.x); v.y = fast_tanh(v.y);
                v.z = fast_tanh(v.z); v.w = fast_tanh(v.w);
                *(float4*)&As[r][c + j] = v;
            }
        }
        __syncthreads();
        #pragma unroll
        for (int hh = 0; hh < 64; hh += 4) {
            float4 w  = *(const float4*)&Ws[o][kb + hh];
            float4 v0 = *(const float4*)&As[rg * 4 + 0][hh];
            float4 v1 = *(const float4*)&As[rg * 4 + 1][hh];
            float4 v2 = *(const float4*)&As[rg * 4 + 2][hh];
            float4 v3 = *(const float4*)&As[rg * 4 + 3][hh];
            acc0 += v0.x * w.x + v0.y * w.y + v0.z * w.z + v0.w * w.w;
            acc1 += v1.x * w.x + v1.y * w.y + v1.z * w.z + v1.w * w.w;
            acc2 += v2.x * w.x + v2.y * w.y + v2.z * w.z + v2.w * w.w;
            acc3 += v3.x * w.x + v3.y * w.y + v3.z * w.z + v3.w * w.w;
        }
    }

    const float bo = Wout_b[o];
    out[(size_t)(row0 + rg * 4 + 0) * kO + o] = acc0 + bo;
    out[(size_t)(row0 + rg * 4 + 1) * kO + o] = acc1 + bo;
    out[(size_t)(row0 + rg * 4 + 2) * kO + o] = acc2 + bo;
    out[(size_t)(row0 + rg * 4 + 3) * kO + o] = acc3 + bo;
}

extern "C" void kernel_launch(void* const* d_in, const int* in_sizes, int n_in,
                              void* d_out, int out_size, void* d_ws, size_t ws_size,
                              hipStream_t stream) {
    const float* u      = (const float*)d_in[0];
    const float* x0     = (const float*)d_in[1];
    const float* noise  = (const float*)d_in[2];
    const float* Win_w  = (const float*)d_in[3];
    const float* Win_b  = (const float*)d_in[4];
    const float* Wout_w = (const float*)d_in[5];
    const float* Wout_b = (const float*)d_in[6];
    const float* M_rnn  = (const float*)d_in[7];
    const float* N_rnn  = (const float*)d_in[8];
    const float* L_tb   = (const float*)d_in[9];
    const float* M_tb   = (const float*)d_in[10];
    const float* N_tb   = (const float*)d_in[11];

    float* out  = (float*)d_out;                       // [B,T,O]
    float* xfin = out + (size_t)kB * kT * kO;          // [B,H]
    float* traj = xfin + (size_t)kB * kH;              // [B,T,H]

    scan_kernel<<<dim3(kB), dim3(kH), 0, stream>>>(
        u, x0, noise, Win_w, Win_b, M_rnn, N_rnn, L_tb, M_tb, N_tb, traj, xfin);
    out_kernel<<<dim3((kB * kT) / 32), dim3(256), 0, stream>>>(
        traj, Wout_w, Wout_b, out);
}